// Round 12
// baseline (187.635 us; speedup 1.0000x reference)
//
#include <hip/hip_runtime.h>
#include <hip/hip_bf16.h>
#include <math.h>

#define B_N    32768
#define XD     60
#define YD     10
#define NK     64
#define HID    2048
#define OUTD   704   // NK + NK*YD
#define TS     64    // rows per tile
#define MAXT   576   // >= 512 full tiles + 64 partials; divisible by 8 (XCD swizzle)
#define NW     8     // waves per block
#define NSLAB  8     // slabs per wave (NW*NSLAB*32 == HID)

#define LBLK   128   // label blocks (B/256)

typedef __bf16 bf16x8_t __attribute__((ext_vector_type(8)));
typedef float  f32x4_t  __attribute__((ext_vector_type(4)));

union Frag { uint4 q; bf16x8_t v; };

#define MFMA16(a, b, c) __builtin_amdgcn_mfma_f32_16x16x32_bf16(a, b, c, 0, 0, 0)

__device__ __forceinline__ unsigned short bf16bits(float f) {
    __hip_bfloat16 h = __float2bfloat16(f);
    return *reinterpret_cast<unsigned short*>(&h);
}

// ---------------- merged prep: labels+counts | W1P | W2P | W2G packs ----------
// Fragment-major packing: record f (= hid-slice index, hid cols [32f,32f+32))
// holds 64 lanes x 16B contiguous; k_fused loads are base + lane*16B.
__global__ __launch_bounds__(256) void k_prep(const float* __restrict__ y,
                                              const float* __restrict__ centers,
                                              const float* __restrict__ W1,
                                              const float* __restrict__ W2,
                                              int* __restrict__ labels,
                                              int* __restrict__ counts,
                                              unsigned short* __restrict__ W1P,
                                              unsigned short* __restrict__ W2P,
                                              unsigned short* __restrict__ W2G) {
    __shared__ __align__(16) char smem[40960];
    int bid = blockIdx.x, t = threadIdx.x;
    int l  = t & 63;
    int lr = l & 15;
    int lg = l >> 4;

    if (bid < LBLK) {
        float* cs = (float*)smem; float* sc = cs + 640; int* lh = (int*)(cs + 704);
        for (int i = t; i < NK * YD; i += 256) cs[i] = centers[i];
        if (t < NK) lh[t] = 0;
        __syncthreads();
        if (t < NK) { float s = 0.f; for (int j = 0; j < YD; ++j) { float v = cs[t*YD+j]; s += v*v; } sc[t] = s; }
        __syncthreads();
        int i = bid * 256 + t;
        float ly[YD]; float sy = 0.f;
        for (int j = 0; j < YD; ++j) { ly[j] = y[i*YD+j]; sy += ly[j]*ly[j]; }
        float best = 1e30f; int lab = 0;
        for (int k = 0; k < NK; ++k) {
            float dot = 0.f;
            #pragma unroll
            for (int j = 0; j < YD; ++j) dot += ly[j] * cs[k*YD+j];
            float d = sy - 2.f*dot + sc[k];
            if (d < best) { best = d; lab = k; }
        }
        labels[i] = lab;
        atomicAdd(&lh[lab], 1);
        __syncthreads();
        if (t < NK && lh[t] > 0) atomicAdd(&counts[t], lh[t]);
    } else if (bid < LBLK + 64) {
        int b = bid - LBLK, s = b >> 2, w = b & 3;   // f = s*4+w covers hid 32f
        unsigned short (*lds)[32] = (unsigned short(*)[32])smem;
        int n0 = 128*s + 32*w;
        for (int idx = t; idx < 64*32; idx += 256) {
            int kk = idx >> 5, c = idx & 31;
            float v = (kk < XD) ? W1[(size_t)(YD + kk) * HID + n0 + c] : 0.f;
            lds[kk][c] = bf16bits(v);
        }
        __syncthreads();
        int n2 = t >> 7, ks = (t >> 6) & 1;
        ushort2 o[4];
        #pragma unroll
        for (int jj = 0; jj < 4; ++jj) {
            o[jj].x = lds[32*ks + 8*lg + 2*jj    ][16*n2 + lr];
            o[jj].y = lds[32*ks + 8*lg + 2*jj + 1][16*n2 + lr];
        }
        *reinterpret_cast<uint4*>(&W1P[((((s*4 + w)*2 + n2)*2 + ks) << 9) + l*8]) =
            *reinterpret_cast<uint4*>(o);
    } else if (bid < LBLK + 128) {
        int b = bid - LBLK - 64, s = b >> 2, w = b & 3;
        unsigned short (*lds)[64] = (unsigned short(*)[64])smem;
        int k0 = 128*s + 32*w;
        for (int idx = t; idx < 32*64; idx += 256) {
            int kk = idx >> 6, c = idx & 63;
            lds[kk][c] = bf16bits(W2[(size_t)(k0 + kk) * OUTD + c]);
        }
        __syncthreads();
        int nt = t >> 6;
        ushort2 o[4];
        #pragma unroll
        for (int jj = 0; jj < 4; ++jj) {
            o[jj].x = lds[8*lg + 2*jj    ][16*nt + lr];
            o[jj].y = lds[8*lg + 2*jj + 1][16*nt + lr];
        }
        *reinterpret_cast<uint4*>(&W2P[(((s*4 + w)*4 + nt) << 9) + l*8]) =
            *reinterpret_cast<uint4*>(o);
    } else {
        int b = bid - LBLK - 128, s = b >> 2, w = b & 3;
        unsigned short (*lds)[640] = (unsigned short(*)[640])smem;
        int k0 = 128*s + 32*w;
        for (int idx = t; idx < 32*640; idx += 256) {
            int kk = idx / 640, c = idx - kk*640;
            lds[kk][c] = bf16bits(W2[(size_t)(k0 + kk) * OUTD + NK + c]);
        }
        __syncthreads();
        for (int g = t >> 6; g < 64; g += 4) {
            ushort2 o[4];
            #pragma unroll
            for (int jj = 0; jj < 4; ++jj) {
                o[jj].x = (lr < YD) ? lds[8*lg + 2*jj    ][10*g + lr] : (unsigned short)0;
                o[jj].y = (lr < YD) ? lds[8*lg + 2*jj + 1][10*g + lr] : (unsigned short)0;
            }
            *reinterpret_cast<uint4*>(&W2G[(((g*16 + s)*4 + w) << 9) + l*8]) =
                *reinterpret_cast<uint4*>(o);
        }
    }
}

// ---------------- wave-parallel scan + tile-descriptor build ----------
__global__ void k_scan(const int* __restrict__ counts, int* __restrict__ cursor,
                       int* __restrict__ tile_g, int* __restrict__ tile_off,
                       int* __restrict__ tile_n) {
    int t = threadIdx.x;
    int c = counts[t];
    int ntm = (c + TS - 1) / TS;
    int sc = c, st = ntm;
    #pragma unroll
    for (int d = 1; d < 64; d <<= 1) {
        int vc = __shfl_up(sc, d);
        int vt = __shfl_up(st, d);
        if (t >= d) { sc += vc; st += vt; }
    }
    int off   = sc - c;
    int tbase = st - ntm;
    cursor[t] = off;
    for (int i = 0; i < ntm; ++i) {
        tile_g[tbase + i]   = t;
        tile_off[tbase + i] = off + TS * i;
        tile_n[tbase + i]   = min(TS, c - TS * i);
    }
    int total = __shfl(st, 63);
    for (int i = total + t; i < MAXT; i += 64) tile_n[i] = 0;
}

// ---------------- scatter ----------
__global__ __launch_bounds__(256) void k_scatter(const int* __restrict__ labels,
                                                 int* __restrict__ cursor,
                                                 int* __restrict__ perm) {
    __shared__ int lh[NK], lbase[NK];
    int t = threadIdx.x;
    if (t < NK) lh[t] = 0;
    __syncthreads();
    int i = blockIdx.x * 256 + t;
    int lab = labels[i];
    int rank = atomicAdd(&lh[lab], 1);
    __syncthreads();
    if (t < NK && lh[t] > 0) lbase[t] = atomicAdd(&cursor[t], lh[t]);
    __syncthreads();
    perm[lbase[lab] + rank] = i;
}

// ---------------- fused: one 64-row single-group tile per block, 8 waves.
// Wave w owns hid-slices f = s*8+w, s in [0,8). Same slice in GEMM1 (produce)
// and GEMM2 K-split (consume) -> h exchange intra-wave, barrier-free slab loop.
// Simple loop (no manual pipeline): TLP from 8 waves/block covers load latency.
__global__ __launch_bounds__(512, 4) void k_fused(const float* __restrict__ x,
                                                  const unsigned short* __restrict__ W1P,
                                                  const float* __restrict__ b1,
                                                  const unsigned short* __restrict__ W2P,
                                                  const unsigned short* __restrict__ W2G,
                                                  const float* __restrict__ b2,
                                                  const float* __restrict__ y,
                                                  const float* __restrict__ centers,
                                                  const int* __restrict__ tile_g,
                                                  const int* __restrict__ tile_off,
                                                  const int* __restrict__ tile_n,
                                                  const int* __restrict__ perm,
                                                  float* __restrict__ accum) {
    __shared__ __align__(16) union {
        struct { unsigned short x[TS][80]; uint2 h[NW][TS][9]; } a;  // 10240 + 36864 B
        float o[TS][84];                                             // 21504 B
    } u;
    __shared__ int   rows_s[TS];
    __shared__ float red_ce[TS], red_mse[TS];

    int phys = blockIdx.x, t = threadIdx.x;
    int bid  = (phys & 7) * (MAXT / 8) + (phys >> 3);   // XCD chunk swizzle (bijective)
    int nrows = tile_n[bid];
    if (nrows == 0) return;
    int g   = tile_g[bid];
    int off = tile_off[bid];

    int w  = t >> 6;          // wave 0..7
    int l  = t & 63;
    int lr = l & 15;
    int lg = l >> 4;

    if (t < TS) rows_s[t] = (t < nrows) ? perm[off + t] : -1;
    __syncthreads();

    // gather x rows -> LDS bf16, vectorized float4; c4==15 zero-pads 60..79
    {
        int c4 = t & 15;
        #pragma unroll
        for (int it = 0; it < 2; ++it) {
            int r = 32 * it + (t >> 4);
            int row = rows_s[r];
            ushort4 pk = {0, 0, 0, 0};
            if (row >= 0 && c4 < 15) {
                float4 v = *reinterpret_cast<const float4*>(&x[(size_t)row * XD + 4 * c4]);
                pk.x = bf16bits(v.x); pk.y = bf16bits(v.y);
                pk.z = bf16bits(v.z); pk.w = bf16bits(v.w);
            }
            *reinterpret_cast<ushort4*>(&u.a.x[r][4 * c4]) = pk;
            if (c4 == 15) {
                ushort4 z = {0, 0, 0, 0};
                *reinterpret_cast<ushort4*>(&u.a.x[r][64]) = z;
                *reinterpret_cast<ushort4*>(&u.a.x[r][68]) = z;
                *reinterpret_cast<ushort4*>(&u.a.x[r][72]) = z;
                *reinterpret_cast<ushort4*>(&u.a.x[r][76]) = z;
            }
        }
    }
    __syncthreads();   // the ONLY barrier before the epilogue

    Frag xf[4][2];
    #pragma unroll
    for (int mt = 0; mt < 4; ++mt)
        #pragma unroll
        for (int ks = 0; ks < 2; ++ks)
            xf[mt][ks].q = *reinterpret_cast<const uint4*>(&u.a.x[16*mt + lr][32*ks + 8*lg]);

    f32x4_t acc2[4][5];
    #pragma unroll
    for (int mt = 0; mt < 4; ++mt)
        #pragma unroll
        for (int nt = 0; nt < 5; ++nt) acc2[mt][nt] = (f32x4_t){0.f, 0.f, 0.f, 0.f};

    uint2* hw = &u.a.h[w][0][0];

    for (int s = 0; s < NSLAB; ++s) {
        int f = s * NW + w;          // hid-slice index: cols [32f, 32f+32)
        // ---- packed weight loads (coalesced: base + l*16B)
        Frag w0, w1, w2, w3; float v0, v1;
        int f1 = (f << 11) + l*8;
        w0.q = *reinterpret_cast<const uint4*>(&W1P[f1]);
        w1.q = *reinterpret_cast<const uint4*>(&W1P[f1 + 512]);
        w2.q = *reinterpret_cast<const uint4*>(&W1P[f1 + 1024]);
        w3.q = *reinterpret_cast<const uint4*>(&W1P[f1 + 1536]);
        int kb = f*32 + lr;
        v0 = b1[kb]; v1 = b1[kb + 16];
        Frag q0, q1, q2, q3, q4;
        int f2 = (f << 11) + l*8;
        q0.q = *reinterpret_cast<const uint4*>(&W2P[f2]);
        q1.q = *reinterpret_cast<const uint4*>(&W2P[f2 + 512]);
        q2.q = *reinterpret_cast<const uint4*>(&W2P[f2 + 1024]);
        q3.q = *reinterpret_cast<const uint4*>(&W2P[f2 + 1536]);
        q4.q = *reinterpret_cast<const uint4*>(&W2G[((g*64 + f) << 9) + l*8]);

        // ---- GEMM1 (swapped): 32 hid cols of slice f; pack -> per-wave scratch
        #pragma unroll
        for (int mt = 0; mt < 4; ++mt) {
            f32x4_t h0 = {0.f, 0.f, 0.f, 0.f}, h1 = {0.f, 0.f, 0.f, 0.f};
            h0 = MFMA16(w0.v, xf[mt][0].v, h0);
            h0 = MFMA16(w1.v, xf[mt][1].v, h0);
            h1 = MFMA16(w2.v, xf[mt][0].v, h1);
            h1 = MFMA16(w3.v, xf[mt][1].v, h1);
            ushort4 p0, p1;
            p0.x = bf16bits(fmaxf(h0[0] + v0, 0.f));
            p0.y = bf16bits(fmaxf(h0[1] + v0, 0.f));
            p0.z = bf16bits(fmaxf(h0[2] + v0, 0.f));
            p0.w = bf16bits(fmaxf(h0[3] + v0, 0.f));
            p1.x = bf16bits(fmaxf(h1[0] + v1, 0.f));
            p1.y = bf16bits(fmaxf(h1[1] + v1, 0.f));
            p1.z = bf16bits(fmaxf(h1[2] + v1, 0.f));
            p1.w = bf16bits(fmaxf(h1[3] + v1, 0.f));
            uint2* hrow = hw + (16*mt + lr) * 9;
            hrow[lg]     = *reinterpret_cast<uint2*>(&p0);
            hrow[4 + lg] = *reinterpret_cast<uint2*>(&p1);
        }
        // ---- GEMM2 (swapped, K-split): consume own slice (intra-wave in-order DS)
        #pragma unroll
        for (int mt = 0; mt < 4; ++mt) {
            uint2 lo = hw[(16*mt + lr) * 9 + 2*lg];
            uint2 hi = hw[(16*mt + lr) * 9 + 2*lg + 1];
            Frag a2; a2.q = make_uint4(lo.x, lo.y, hi.x, hi.y);
            acc2[mt][0] = MFMA16(q0.v, a2.v, acc2[mt][0]);
            acc2[mt][1] = MFMA16(q1.v, a2.v, acc2[mt][1]);
            acc2[mt][2] = MFMA16(q2.v, a2.v, acc2[mt][2]);
            acc2[mt][3] = MFMA16(q3.v, a2.v, acc2[mt][3]);
            acc2[mt][4] = MFMA16(q4.v, a2.v, acc2[mt][4]);
        }
    }
    __syncthreads();   // all x/h use done before overlaying u.o

    // epilogue: sum 8 K-partials, bias in phase 0
    for (int wv = 0; wv < NW; ++wv) {
        if (w == wv) {
            #pragma unroll
            for (int mt = 0; mt < 4; ++mt)
                #pragma unroll
                for (int nt = 0; nt < 5; ++nt) {
                    float4 v;
                    v.x = acc2[mt][nt][0]; v.y = acc2[mt][nt][1];
                    v.z = acc2[mt][nt][2]; v.w = acc2[mt][nt][3];
                    float4* pp = reinterpret_cast<float4*>(&u.o[16*mt + lr][16*nt + 4*lg]);
                    if (wv == 0) {
                        float bx, by, bz, bw;
                        if (nt < 4) {
                            int c = 16*nt + 4*lg;
                            bx = b2[c]; by = b2[c+1]; bz = b2[c+2]; bw = b2[c+3];
                        } else {
                            int c = 4*lg;
                            bx = (c   < YD) ? b2[NK + g*YD + c  ] : 0.f;
                            by = (c+1 < YD) ? b2[NK + g*YD + c+1] : 0.f;
                            bz = (c+2 < YD) ? b2[NK + g*YD + c+2] : 0.f;
                            bw = (c+3 < YD) ? b2[NK + g*YD + c+3] : 0.f;
                        }
                        v.x += bx; v.y += by; v.z += bz; v.w += bw;
                        *pp = v;
                    } else {
                        float4 cur = *pp;
                        cur.x += v.x; cur.y += v.y; cur.z += v.z; cur.w += v.w;
                        *pp = cur;
                    }
                }
        }
        __syncthreads();
    }

    if (t < TS) {
        float ce_v = 0.f, mse_v = 0.f;
        if (t < nrows) {
            float m = -1e30f;
            for (int c = 0; c < NK; ++c) m = fmaxf(m, u.o[t][c]);
            float s2 = 0.f;
            for (int c = 0; c < NK; ++c) s2 += expf(u.o[t][c] - m);
            float lse = m + logf(s2);
            ce_v = lse - u.o[t][g];
            int row = rows_s[t];
            #pragma unroll
            for (int j = 0; j < YD; ++j) {
                float tr = y[row * YD + j] - centers[g * YD + j];
                float d  = tr - u.o[t][NK + j];
                mse_v += d * d;
            }
        }
        red_ce[t] = ce_v; red_mse[t] = mse_v;
    }
    __syncthreads();
    if (t == 0) {
        float sc = 0.f, sm = 0.f;
        for (int i = 0; i < TS; ++i) { sc += red_ce[i]; sm += red_mse[i]; }
        atomicAdd(&accum[0], sc);
        atomicAdd(&accum[1], sm);
    }
}

__global__ void k_final(const float* __restrict__ accum, float* __restrict__ out) {
    out[0] = accum[0] / (float)B_N + 100.f * accum[1] / ((float)B_N * (float)YD);
}

extern "C" void kernel_launch(void* const* d_in, const int* in_sizes, int n_in,
                              void* d_out, int out_size, void* d_ws, size_t ws_size,
                              hipStream_t stream) {
    const float* x       = (const float*)d_in[0];
    const float* y       = (const float*)d_in[1];
    const float* centers = (const float*)d_in[2];
    const float* W1      = (const float*)d_in[3];
    const float* b1      = (const float*)d_in[4];
    const float* W2      = (const float*)d_in[5];
    const float* b2      = (const float*)d_in[6];

    char* ws = (char*)d_ws;
    float* accum  = (float*)ws;                        // 2 f32 @ 0
    int* counts   = (int*)(ws + 256);                  // 64 ints
    int* cursor   = (int*)(ws + 768);
    int* tile_g   = (int*)(ws + 1024);                 // MAXT
    int* tile_off = (int*)(ws + 1024 + 4 * MAXT);
    int* tile_n   = (int*)(ws + 1024 + 8 * MAXT);
    char* ws2     = ws + 1024 + 12 * MAXT + 256;
    int* labels   = (int*)ws2;                               // 128 KB
    int* perm     = (int*)(ws2 + 131072);                    // 128 KB
    unsigned short* W1P = (unsigned short*)(ws2 + 262144);   // 256 KB
    unsigned short* W2P = (unsigned short*)(ws2 + 524288);   // 256 KB
    unsigned short* W2G = (unsigned short*)(ws2 + 786432);   // 4 MB

    hipMemsetAsync(ws, 0, 1024, stream);   // zero accum + counts
    k_prep   <<<LBLK + 192, 256, 0, stream>>>(y, centers, W1, W2,
                                              labels, counts, W1P, W2P, W2G);
    k_scan   <<<1, 64, 0, stream>>>(counts, cursor, tile_g, tile_off, tile_n);
    k_scatter<<<B_N / 256, 256, 0, stream>>>(labels, cursor, perm);
    k_fused  <<<MAXT, 512, 0, stream>>>(x, W1P, b1, W2P, W2G, b2, y, centers,
                                        tile_g, tile_off, tile_n, perm, accum);
    k_final  <<<1, 1, 0, stream>>>(accum, (float*)d_out);
}

// Round 13
// 78.890 us; speedup vs baseline: 2.3784x; 2.3784x over previous
//
#include <hip/hip_runtime.h>
#include <hip/hip_bf16.h>
#include <math.h>

#define B_N    32768
#define XD     60
#define YD     10
#define NK     64
#define HID    2048
#define OUTD   704   // NK + NK*YD
#define TS     64    // rows per tile
#define MAXT   576   // >= 512 full tiles + 64 partials; divisible by 8 (XCD swizzle)

#define LBLK   128   // label blocks (B/256)

typedef __bf16 bf16x8_t __attribute__((ext_vector_type(8)));
typedef float  f32x4_t  __attribute__((ext_vector_type(4)));

union Frag { uint4 q; bf16x8_t v; };

#define MFMA16(a, b, c) __builtin_amdgcn_mfma_f32_16x16x32_bf16(a, b, c, 0, 0, 0)

__device__ __forceinline__ unsigned short bf16bits(float f) {
    __hip_bfloat16 h = __float2bfloat16(f);
    return *reinterpret_cast<unsigned short*>(&h);
}

// ---------------- merged prep: labels+counts | W1P | W2P | W2G packs ----------
__global__ __launch_bounds__(256) void k_prep(const float* __restrict__ y,
                                              const float* __restrict__ centers,
                                              const float* __restrict__ W1,
                                              const float* __restrict__ W2,
                                              int* __restrict__ labels,
                                              int* __restrict__ counts,
                                              unsigned short* __restrict__ W1P,
                                              unsigned short* __restrict__ W2P,
                                              unsigned short* __restrict__ W2G) {
    __shared__ __align__(16) char smem[40960];
    int bid = blockIdx.x, t = threadIdx.x;
    int l  = t & 63;
    int lr = l & 15;
    int lg = l >> 4;

    if (bid < LBLK) {
        float* cs = (float*)smem; float* sc = cs + 640; int* lh = (int*)(cs + 704);
        for (int i = t; i < NK * YD; i += 256) cs[i] = centers[i];
        if (t < NK) lh[t] = 0;
        __syncthreads();
        if (t < NK) { float s = 0.f; for (int j = 0; j < YD; ++j) { float v = cs[t*YD+j]; s += v*v; } sc[t] = s; }
        __syncthreads();
        int i = bid * 256 + t;
        float ly[YD]; float sy = 0.f;
        for (int j = 0; j < YD; ++j) { ly[j] = y[i*YD+j]; sy += ly[j]*ly[j]; }
        float best = 1e30f; int lab = 0;
        for (int k = 0; k < NK; ++k) {
            float dot = 0.f;
            #pragma unroll
            for (int j = 0; j < YD; ++j) dot += ly[j] * cs[k*YD+j];
            float d = sy - 2.f*dot + sc[k];
            if (d < best) { best = d; lab = k; }
        }
        labels[i] = lab;
        atomicAdd(&lh[lab], 1);
        __syncthreads();
        if (t < NK && lh[t] > 0) atomicAdd(&counts[t], lh[t]);
    } else if (bid < LBLK + 64) {
        int b = bid - LBLK, s = b >> 2, w = b & 3;
        unsigned short (*lds)[32] = (unsigned short(*)[32])smem;
        int n0 = 128*s + 32*w;
        for (int idx = t; idx < 64*32; idx += 256) {
            int kk = idx >> 5, c = idx & 31;
            float v = (kk < XD) ? W1[(size_t)(YD + kk) * HID + n0 + c] : 0.f;
            lds[kk][c] = bf16bits(v);
        }
        __syncthreads();
        int n2 = t >> 7, ks = (t >> 6) & 1;
        ushort2 o[4];
        #pragma unroll
        for (int jj = 0; jj < 4; ++jj) {
            o[jj].x = lds[32*ks + 8*lg + 2*jj    ][16*n2 + lr];
            o[jj].y = lds[32*ks + 8*lg + 2*jj + 1][16*n2 + lr];
        }
        *reinterpret_cast<uint4*>(&W1P[((((s*4 + w)*2 + n2)*2 + ks) << 9) + l*8]) =
            *reinterpret_cast<uint4*>(o);
    } else if (bid < LBLK + 128) {
        int b = bid - LBLK - 64, s = b >> 2, w = b & 3;
        unsigned short (*lds)[64] = (unsigned short(*)[64])smem;
        int k0 = 128*s + 32*w;
        for (int idx = t; idx < 32*64; idx += 256) {
            int kk = idx >> 6, c = idx & 63;
            lds[kk][c] = bf16bits(W2[(size_t)(k0 + kk) * OUTD + c]);
        }
        __syncthreads();
        int nt = t >> 6;
        ushort2 o[4];
        #pragma unroll
        for (int jj = 0; jj < 4; ++jj) {
            o[jj].x = lds[8*lg + 2*jj    ][16*nt + lr];
            o[jj].y = lds[8*lg + 2*jj + 1][16*nt + lr];
        }
        *reinterpret_cast<uint4*>(&W2P[(((s*4 + w)*4 + nt) << 9) + l*8]) =
            *reinterpret_cast<uint4*>(o);
    } else {
        int b = bid - LBLK - 128, s = b >> 2, w = b & 3;
        unsigned short (*lds)[640] = (unsigned short(*)[640])smem;
        int k0 = 128*s + 32*w;
        for (int idx = t; idx < 32*640; idx += 256) {
            int kk = idx / 640, c = idx - kk*640;
            lds[kk][c] = bf16bits(W2[(size_t)(k0 + kk) * OUTD + NK + c]);
        }
        __syncthreads();
        for (int g = t >> 6; g < 64; g += 4) {
            ushort2 o[4];
            #pragma unroll
            for (int jj = 0; jj < 4; ++jj) {
                o[jj].x = (lr < YD) ? lds[8*lg + 2*jj    ][10*g + lr] : (unsigned short)0;
                o[jj].y = (lr < YD) ? lds[8*lg + 2*jj + 1][10*g + lr] : (unsigned short)0;
            }
            *reinterpret_cast<uint4*>(&W2G[(((g*16 + s)*4 + w) << 9) + l*8]) =
                *reinterpret_cast<uint4*>(o);
        }
    }
}

// ---------------- wave-parallel scan + tile-descriptor build ----------
__global__ void k_scan(const int* __restrict__ counts, int* __restrict__ cursor,
                       int* __restrict__ tile_g, int* __restrict__ tile_off,
                       int* __restrict__ tile_n) {
    int t = threadIdx.x;
    int c = counts[t];
    int ntm = (c + TS - 1) / TS;
    int sc = c, st = ntm;
    #pragma unroll
    for (int d = 1; d < 64; d <<= 1) {
        int vc = __shfl_up(sc, d);
        int vt = __shfl_up(st, d);
        if (t >= d) { sc += vc; st += vt; }
    }
    int off   = sc - c;
    int tbase = st - ntm;
    cursor[t] = off;
    for (int i = 0; i < ntm; ++i) {
        tile_g[tbase + i]   = t;
        tile_off[tbase + i] = off + TS * i;
        tile_n[tbase + i]   = min(TS, c - TS * i);
    }
    int total = __shfl(st, 63);
    for (int i = total + t; i < MAXT; i += 64) tile_n[i] = 0;
}

// ---------------- scatter ----------
__global__ __launch_bounds__(256) void k_scatter(const int* __restrict__ labels,
                                                 int* __restrict__ cursor,
                                                 int* __restrict__ perm) {
    __shared__ int lh[NK], lbase[NK];
    int t = threadIdx.x;
    if (t < NK) lh[t] = 0;
    __syncthreads();
    int i = blockIdx.x * 256 + t;
    int lab = labels[i];
    int rank = atomicAdd(&lh[lab], 1);
    __syncthreads();
    if (t < NK && lh[t] > 0) lbase[t] = atomicAdd(&cursor[t], lh[t]);
    __syncthreads();
    perm[lbase[lab] + rank] = i;
}

// per-slab weight registers (named fields only -> VGPRs)
struct WRegs {
    Frag w0, w1, w2, w3;      // GEMM1: 4 W1P records
    Frag q0, q1, q2, q3, q4;  // GEMM2: 4 W2P + 1 W2G records
    float v0, v1;             // b1 biases
};

__device__ __forceinline__ void loadw(WRegs& r, int s_,
                                      const unsigned short* __restrict__ W1P,
                                      const unsigned short* __restrict__ W2P,
                                      const unsigned short* __restrict__ W2G,
                                      const float* __restrict__ b1,
                                      int g, int w, int l, int lr) {
    int f1 = (((s_*4 + w)*2) << 10) + l*8;
    r.w0.q = *reinterpret_cast<const uint4*>(&W1P[f1]);
    r.w1.q = *reinterpret_cast<const uint4*>(&W1P[f1 + 512]);
    r.w2.q = *reinterpret_cast<const uint4*>(&W1P[f1 + 1024]);
    r.w3.q = *reinterpret_cast<const uint4*>(&W1P[f1 + 1536]);
    int f2 = (((s_*4 + w)*4) << 9) + l*8;
    r.q0.q = *reinterpret_cast<const uint4*>(&W2P[f2]);
    r.q1.q = *reinterpret_cast<const uint4*>(&W2P[f2 + 512]);
    r.q2.q = *reinterpret_cast<const uint4*>(&W2P[f2 + 1024]);
    r.q3.q = *reinterpret_cast<const uint4*>(&W2P[f2 + 1536]);
    r.q4.q = *reinterpret_cast<const uint4*>(&W2G[(((g*16 + s_)*4 + w) << 9) + l*8]);
    int kb = s_*128 + 32*w + lr;
    r.v0 = b1[kb]; r.v1 = b1[kb + 16];
}

__device__ __forceinline__ void slab_body(const WRegs& r,
                                          const Frag (&xf)[4][2], f32x4_t (&acc2)[4][5],
                                          uint2* hw, int lr, int lg) {
    // GEMM1 (swapped): this wave's 32 hid cols; pack per-mt to LDS scratch
    #pragma unroll
    for (int mt = 0; mt < 4; ++mt) {
        f32x4_t h0 = {0.f, 0.f, 0.f, 0.f}, h1 = {0.f, 0.f, 0.f, 0.f};
        h0 = MFMA16(r.w0.v, xf[mt][0].v, h0);
        h0 = MFMA16(r.w1.v, xf[mt][1].v, h0);
        h1 = MFMA16(r.w2.v, xf[mt][0].v, h1);
        h1 = MFMA16(r.w3.v, xf[mt][1].v, h1);
        ushort4 p0, p1;
        p0.x = bf16bits(fmaxf(h0[0] + r.v0, 0.f));
        p0.y = bf16bits(fmaxf(h0[1] + r.v0, 0.f));
        p0.z = bf16bits(fmaxf(h0[2] + r.v0, 0.f));
        p0.w = bf16bits(fmaxf(h0[3] + r.v0, 0.f));
        p1.x = bf16bits(fmaxf(h1[0] + r.v1, 0.f));
        p1.y = bf16bits(fmaxf(h1[1] + r.v1, 0.f));
        p1.z = bf16bits(fmaxf(h1[2] + r.v1, 0.f));
        p1.w = bf16bits(fmaxf(h1[3] + r.v1, 0.f));
        uint2* hrow = hw + (16*mt + lr) * 9;
        hrow[lg]     = *reinterpret_cast<uint2*>(&p0);
        hrow[4 + lg] = *reinterpret_cast<uint2*>(&p1);
    }
    // GEMM2 (swapped, K-split): consume own hid slice (intra-wave in-order DS)
    #pragma unroll
    for (int mt = 0; mt < 4; ++mt) {
        uint2 lo = hw[(16*mt + lr) * 9 + 2*lg];
        uint2 hi = hw[(16*mt + lr) * 9 + 2*lg + 1];
        Frag a2; a2.q = make_uint4(lo.x, lo.y, hi.x, hi.y);
        acc2[mt][0] = MFMA16(r.q0.v, a2.v, acc2[mt][0]);
        acc2[mt][1] = MFMA16(r.q1.v, a2.v, acc2[mt][1]);
        acc2[mt][2] = MFMA16(r.q2.v, a2.v, acc2[mt][2]);
        acc2[mt][3] = MFMA16(r.q3.v, a2.v, acc2[mt][3]);
        acc2[mt][4] = MFMA16(r.q4.v, a2.v, acc2[mt][4]);
    }
}

// ---------------- fused: one 64-row single-group tile per block, 4 waves.
// Depth-2 register prefetch PINNED with sched_barrier(0): the 9 loads of slab
// s+1 must issue as a cluster before slab s's compute; the compiler then emits
// counted vmcnt waits and the load latency hides under 36 MFMAs + pack.
__global__ __launch_bounds__(256, 2) void k_fused(const float* __restrict__ x,
                                                  const unsigned short* __restrict__ W1P,
                                                  const float* __restrict__ b1,
                                                  const unsigned short* __restrict__ W2P,
                                                  const unsigned short* __restrict__ W2G,
                                                  const float* __restrict__ b2,
                                                  const float* __restrict__ y,
                                                  const float* __restrict__ centers,
                                                  const int* __restrict__ tile_g,
                                                  const int* __restrict__ tile_off,
                                                  const int* __restrict__ tile_n,
                                                  const int* __restrict__ perm,
                                                  float* __restrict__ accum) {
    __shared__ __align__(16) union {
        struct { unsigned short x[TS][80]; uint2 h[4][TS][9]; } a;   // 10240 + 18432 B
        float o[TS][84];                                             // 21504 B
    } u;
    __shared__ int   rows_s[TS];
    __shared__ float red_ce[TS], red_mse[TS];

    int phys = blockIdx.x, t = threadIdx.x;
    int bid  = (phys & 7) * (MAXT / 8) + (phys >> 3);   // XCD chunk swizzle (bijective)
    int nrows = tile_n[bid];
    if (nrows == 0) return;
    int g   = tile_g[bid];
    int off = tile_off[bid];

    int w  = t >> 6;
    int l  = t & 63;
    int lr = l & 15;
    int lg = l >> 4;

    if (t < TS) rows_s[t] = (t < nrows) ? perm[off + t] : -1;
    __syncthreads();

    // gather x rows -> LDS bf16, vectorized float4; c4==15 zero-pads 60..79
    {
        int c4 = t & 15;
        #pragma unroll
        for (int it = 0; it < 4; ++it) {
            int r = 16 * it + (t >> 4);
            int row = rows_s[r];
            ushort4 pk = {0, 0, 0, 0};
            if (row >= 0 && c4 < 15) {
                float4 v = *reinterpret_cast<const float4*>(&x[(size_t)row * XD + 4 * c4]);
                pk.x = bf16bits(v.x); pk.y = bf16bits(v.y);
                pk.z = bf16bits(v.z); pk.w = bf16bits(v.w);
            }
            *reinterpret_cast<ushort4*>(&u.a.x[r][4 * c4]) = pk;
            if (c4 == 15) {
                ushort4 z = {0, 0, 0, 0};
                *reinterpret_cast<ushort4*>(&u.a.x[r][64]) = z;
                *reinterpret_cast<ushort4*>(&u.a.x[r][68]) = z;
                *reinterpret_cast<ushort4*>(&u.a.x[r][72]) = z;
                *reinterpret_cast<ushort4*>(&u.a.x[r][76]) = z;
            }
        }
    }
    __syncthreads();   // the ONLY barrier before the epilogue

    Frag xf[4][2];
    #pragma unroll
    for (int mt = 0; mt < 4; ++mt)
        #pragma unroll
        for (int ks = 0; ks < 2; ++ks)
            xf[mt][ks].q = *reinterpret_cast<const uint4*>(&u.a.x[16*mt + lr][32*ks + 8*lg]);

    f32x4_t acc2[4][5];
    #pragma unroll
    for (int mt = 0; mt < 4; ++mt)
        #pragma unroll
        for (int nt = 0; nt < 5; ++nt) acc2[mt][nt] = (f32x4_t){0.f, 0.f, 0.f, 0.f};

    uint2* hw = &u.a.h[w][0][0];

    // depth-2 pipeline, order pinned by sched_barrier(0)
    WRegs rA, rB;
    loadw(rA, 0, W1P, W2P, W2G, b1, g, w, l, lr);
    #pragma unroll 1
    for (int s = 0; s < HID / 128; s += 2) {
        __builtin_amdgcn_sched_barrier(0);
        loadw(rB, s + 1, W1P, W2P, W2G, b1, g, w, l, lr);   // cluster: 9 loads slab s+1
        __builtin_amdgcn_sched_barrier(0);
        slab_body(rA, xf, acc2, hw, lr, lg);                // compute slab s (waits rA only)
        __builtin_amdgcn_sched_barrier(0);
        loadw(rA, (s + 2 < 16) ? s + 2 : 0, W1P, W2P, W2G, b1, g, w, l, lr); // cluster s+2 (tail: dummy)
        __builtin_amdgcn_sched_barrier(0);
        slab_body(rB, xf, acc2, hw, lr, lg);                // compute slab s+1
    }
    __syncthreads();   // all x/h use done before overlaying u.o

    // epilogue: sum 4 K-partials, bias in phase 0
    for (int wv = 0; wv < 4; ++wv) {
        if (w == wv) {
            #pragma unroll
            for (int mt = 0; mt < 4; ++mt)
                #pragma unroll
                for (int nt = 0; nt < 5; ++nt) {
                    float4 v;
                    v.x = acc2[mt][nt][0]; v.y = acc2[mt][nt][1];
                    v.z = acc2[mt][nt][2]; v.w = acc2[mt][nt][3];
                    float4* pp = reinterpret_cast<float4*>(&u.o[16*mt + lr][16*nt + 4*lg]);
                    if (wv == 0) {
                        float bx, by, bz, bw;
                        if (nt < 4) {
                            int c = 16*nt + 4*lg;
                            bx = b2[c]; by = b2[c+1]; bz = b2[c+2]; bw = b2[c+3];
                        } else {
                            int c = 4*lg;
                            bx = (c   < YD) ? b2[NK + g*YD + c  ] : 0.f;
                            by = (c+1 < YD) ? b2[NK + g*YD + c+1] : 0.f;
                            bz = (c+2 < YD) ? b2[NK + g*YD + c+2] : 0.f;
                            bw = (c+3 < YD) ? b2[NK + g*YD + c+3] : 0.f;
                        }
                        v.x += bx; v.y += by; v.z += bz; v.w += bw;
                        *pp = v;
                    } else {
                        float4 cur = *pp;
                        cur.x += v.x; cur.y += v.y; cur.z += v.z; cur.w += v.w;
                        *pp = cur;
                    }
                }
        }
        __syncthreads();
    }

    if (t < TS) {
        float ce_v = 0.f, mse_v = 0.f;
        if (t < nrows) {
            float m = -1e30f;
            for (int c = 0; c < NK; ++c) m = fmaxf(m, u.o[t][c]);
            float s2 = 0.f;
            for (int c = 0; c < NK; ++c) s2 += expf(u.o[t][c] - m);
            float lse = m + logf(s2);
            ce_v = lse - u.o[t][g];
            int row = rows_s[t];
            #pragma unroll
            for (int j = 0; j < YD; ++j) {
                float tr = y[row * YD + j] - centers[g * YD + j];
                float d  = tr - u.o[t][NK + j];
                mse_v += d * d;
            }
        }
        red_ce[t] = ce_v; red_mse[t] = mse_v;
    }
    __syncthreads();
    if (t == 0) {
        float sc = 0.f, sm = 0.f;
        for (int i = 0; i < TS; ++i) { sc += red_ce[i]; sm += red_mse[i]; }
        atomicAdd(&accum[0], sc);
        atomicAdd(&accum[1], sm);
    }
}

__global__ void k_final(const float* __restrict__ accum, float* __restrict__ out) {
    out[0] = accum[0] / (float)B_N + 100.f * accum[1] / ((float)B_N * (float)YD);
}

extern "C" void kernel_launch(void* const* d_in, const int* in_sizes, int n_in,
                              void* d_out, int out_size, void* d_ws, size_t ws_size,
                              hipStream_t stream) {
    const float* x       = (const float*)d_in[0];
    const float* y       = (const float*)d_in[1];
    const float* centers = (const float*)d_in[2];
    const float* W1      = (const float*)d_in[3];
    const float* b1      = (const float*)d_in[4];
    const float* W2      = (const float*)d_in[5];
    const float* b2      = (const float*)d_in[6];

    char* ws = (char*)d_ws;
    float* accum  = (float*)ws;                        // 2 f32 @ 0
    int* counts   = (int*)(ws + 256);                  // 64 ints
    int* cursor   = (int*)(ws + 768);
    int* tile_g   = (int*)(ws + 1024);                 // MAXT
    int* tile_off = (int*)(ws + 1024 + 4 * MAXT);
    int* tile_n   = (int*)(ws + 1024 + 8 * MAXT);
    char* ws2     = ws + 1024 + 12 * MAXT + 256;
    int* labels   = (int*)ws2;                               // 128 KB
    int* perm     = (int*)(ws2 + 131072);                    // 128 KB
    unsigned short* W1P = (unsigned short*)(ws2 + 262144);   // 256 KB
    unsigned short* W2P = (unsigned short*)(ws2 + 524288);   // 256 KB
    unsigned short* W2G = (unsigned short*)(ws2 + 786432);   // 4 MB

    hipMemsetAsync(ws, 0, 1024, stream);   // zero accum + counts
    k_prep   <<<LBLK + 192, 256, 0, stream>>>(y, centers, W1, W2,
                                              labels, counts, W1P, W2P, W2G);
    k_scan   <<<1, 64, 0, stream>>>(counts, cursor, tile_g, tile_off, tile_n);
    k_scatter<<<B_N / 256, 256, 0, stream>>>(labels, cursor, perm);
    k_fused  <<<MAXT, 256, 0, stream>>>(x, W1P, b1, W2P, W2G, b2, y, centers,
                                        tile_g, tile_off, tile_n, perm, accum);
    k_final  <<<1, 1, 0, stream>>>(accum, (float*)d_out);
}